// Round 8
// baseline (499.970 us; speedup 1.0000x reference)
//
#include <hip/hip_runtime.h>

// Problem constants (fixed by reference setup_inputs)
#define B   4
#define C   64      // input channels
#define D   64      // dims per head of q/k/v
#define NN  25      // angRes*angRes angular positions
#define HW  4096    // h*w
#define F   (D*HW)  // 262144 feature dim per head, flattened

#define PT  128     // p-tile per block in k_proj
#define QCH 256     // f elems staged per chunk in k_sqk
#define NCH 4       // chunks per k_sqk block -> block covers 1024 f

typedef unsigned short ushort_t;
typedef unsigned int   uint_t;
typedef __attribute__((ext_vector_type(8)))  short  short8;   // 8 bf16 (4 VGPRs)
typedef __attribute__((ext_vector_type(8)))  unsigned short us8;
typedef __attribute__((ext_vector_type(16))) float  floatx16; // MFMA 32x32 accum
typedef __attribute__((ext_vector_type(4)))  float  f32x4;
typedef __attribute__((ext_vector_type(4)))  unsigned short us4;

// Compensated bf16 weight splits (W = hi + lo, |err| ~ 2^-17 rel), native
// [row][c] layout. Rows 0..127 = q,k; Wv rows 0..63 = v.
__device__ ushort_t g_Wthi[128 * C];
__device__ ushort_t g_Wtlo[128 * C];
__device__ ushort_t g_Wvhi[D * C];
__device__ ushort_t g_Wvlo[D * C];

// Tiny cross-kernel accumulators (20KB) -- frees d_out to host Q,K.
__device__ float g_S[B * NN * NN];
__device__ float g_qq[B * NN];
__device__ float g_kk[B * NN];
__device__ float g_attT[B * NN * NN];   // transposed att [b][m][n]

static __device__ __forceinline__ ushort_t f2bf(float f) {
    uint_t u = __float_as_uint(f);
    u += 0x7FFFu + ((u >> 16) & 1u);   // round-to-nearest-even
    return (ushort_t)(u >> 16);
}
static __device__ __forceinline__ float bf2f(ushort_t h) {
    return __uint_as_float((uint_t)h << 16);
}

// ---- Kp: zero S/qq/kk + split all 192 W rows into bf16 hi/lo. 48 blocks.
__global__ void k_prep(const float* __restrict__ W) {
    int i = blockIdx.x * 256 + threadIdx.x;          // over 192*64
    if (i < 2500)      g_S[i] = 0.f;
    else if (i < 2600) g_qq[i - 2500] = 0.f;
    else if (i < 2700) g_kk[i - 2600] = 0.f;
    if (i < 128 * 64) {
        float w = W[i];                              // W[d'][c], native index
        ushort_t hi = f2bf(w);
        g_Wthi[i] = hi;
        g_Wtlo[i] = f2bf(w - bf2f(hi));
    } else if (i < 192 * 64) {
        float w = W[i];                              // v rows 128..191
        int j = i - 128 * 64;
        ushort_t hi = f2bf(w);
        g_Wvhi[j] = hi;
        g_Wvlo[j] = f2bf(w - bf2f(hi));
    }
}

// ---- K1: fused Q,K,V projection via compensated-bf16 MFMA, LDS-LESS.
// grid (HW/PT, NN, B), 256 thr = 4 waves, NO shared memory, NO barrier.
// Round-6 staged x through LDS (stage->barrier->ds_read): 107us, 2.87M
// bank-conflict cy, serial per block. Here each wave loads its own
// B-fragments straight from global: lane (row,kh) reads 8 c-strided
// floats at its pcol; lanes 0..31 share consecutive p -> each load
// instr = 2x128B segments, and the 32KB x-tile is shared by 4 waves
// (L1/L2-hot). Per pt: load 32 -> convert hi/lo -> 12 MFMA -> store.
// The V phase for wave wv (sv=wv&1, ph=wv>>1) consumes pts {2ph,2ph+1},
// whose B-fragments are the SAME x values -> computed inside the
// matching pt iteration, reusing the fragments (128 loads/wave total).
// Rounding points identical to round 6 -> absmax unchanged.
// Output layout unchanged (packed MFMA C/D order):
//   Q/K elem f = [tile(32)][slab(2)][pt(4)][r4(4)][ln(64)][j(4)]
//   V   elem g = [tile(32)][sv(2)][ph(2)][ptv(2)][r4(4)][ln(64)][j(4)]
__global__ void __launch_bounds__(256, 4)
k_proj(const float* __restrict__ x,
       ushort_t* __restrict__ Q, ushort_t* __restrict__ K,
       float* __restrict__ V) {
    const int t  = threadIdx.x;
    const int wv = t >> 6, ln = t & 63;
    const int n  = blockIdx.y, b = blockIdx.z;
    const int tile = blockIdx.x;
    const int gp0  = tile * PT;
    const int row = ln & 31, kh8 = (ln >> 5) * 8;
    const size_t cstride = (size_t)NN * HW;
    const float* xp = x + ((size_t)(b * C) * NN + n) * HW + gp0;

    // persistent QK A-fragments: W rows d0..d0+31 (Q: 0..63, K: 64..127)
    const int d0 = wv * 32;
    short8 ahi[4], alo[4];
#pragma unroll
    for (int ks = 0; ks < 4; ++ks) {
        ahi[ks] = *(const short8*)&g_Wthi[(d0 + row) * 64 + ks * 16 + kh8];
        alo[ks] = *(const short8*)&g_Wtlo[(d0 + row) * 64 + ks * 16 + kh8];
    }

    ushort_t* __restrict__ O = (wv < 2) ? Q : K;
    const int slab = wv & 1;           // Q slab (wv<2) or K slab (wv>=2)
    const int sv = wv & 1, ph = wv >> 1;
    const size_t nbase = (size_t)(b * NN + n) * F;

    float nrm = 0.f;
#pragma unroll
    for (int pt = 0; pt < 4; ++pt) {
        const int pcol = pt * 32 + row;

        // ---- B-fragments for this pt, straight from global, hi/lo split.
        short8 bhi[4], blo[4];
#pragma unroll
        for (int ks = 0; ks < 4; ++ks) {
            float xv[8];
#pragma unroll
            for (int j = 0; j < 8; ++j)
                xv[j] = xp[(size_t)(ks * 16 + kh8 + j) * cstride + pcol];
#pragma unroll
            for (int j = 0; j < 8; ++j) {
                const ushort_t hi = f2bf(xv[j]);
                bhi[ks][j] = (short)hi;
                blo[ks][j] = (short)f2bf(xv[j] - bf2f(hi));
            }
        }

        // ---- QK: 12 MFMA, packed epilogue store + fp32 pre-round norm.
        floatx16 acc;
#pragma unroll
        for (int r = 0; r < 16; ++r) acc[r] = 0.f;
#pragma unroll
        for (int ks = 0; ks < 4; ++ks) {
            acc = __builtin_amdgcn_mfma_f32_32x32x16_bf16(ahi[ks], bhi[ks], acc, 0, 0, 0);
            acc = __builtin_amdgcn_mfma_f32_32x32x16_bf16(alo[ks], bhi[ks], acc, 0, 0, 0);
            acc = __builtin_amdgcn_mfma_f32_32x32x16_bf16(ahi[ks], blo[ks], acc, 0, 0, 0);
        }
#pragma unroll
        for (int r4 = 0; r4 < 4; ++r4) {
            us4 h;
#pragma unroll
            for (int j = 0; j < 4; ++j) {
                const float a = acc[r4 * 4 + j];
                nrm += a * a;
                h[j] = f2bf(a);
            }
            *(us4*)&O[nbase + (((size_t)((tile * 2 + slab) * 16 + pt * 4 + r4)) << 8)
                      + ln * 4] = h;
        }

        // ---- V: reuse this pt's B-fragments if it belongs to my p-half.
        if ((pt >> 1) == ph) {                    // wave-uniform, compile-time
            const int ptv = pt & 1;
            short8 vhi[4], vlo[4];                // L1-hot reload, transient
#pragma unroll
            for (int ks = 0; ks < 4; ++ks) {
                vhi[ks] = *(const short8*)&g_Wvhi[(sv * 32 + row) * 64 + ks * 16 + kh8];
                vlo[ks] = *(const short8*)&g_Wvlo[(sv * 32 + row) * 64 + ks * 16 + kh8];
            }
            floatx16 av;
#pragma unroll
            for (int r = 0; r < 16; ++r) av[r] = 0.f;
#pragma unroll
            for (int ks = 0; ks < 4; ++ks) {
                av = __builtin_amdgcn_mfma_f32_32x32x16_bf16(vhi[ks], bhi[ks], av, 0, 0, 0);
                av = __builtin_amdgcn_mfma_f32_32x32x16_bf16(vlo[ks], bhi[ks], av, 0, 0, 0);
                av = __builtin_amdgcn_mfma_f32_32x32x16_bf16(vhi[ks], blo[ks], av, 0, 0, 0);
            }
#pragma unroll
            for (int r4 = 0; r4 < 4; ++r4) {
                f32x4 vv;
#pragma unroll
                for (int j = 0; j < 4; ++j) vv[j] = av[r4 * 4 + j];
                *(f32x4*)&V[nbase + (((size_t)((((tile * 2 + sv) * 2 + ph) * 2 + ptv) * 4
                    + r4)) << 8) + ln * 4] = vv;
            }
        }
    }
    for (int off = 32; off > 0; off >>= 1) nrm += __shfl_xor(nrm, off);
    if (ln == 0) atomicAdd(((wv < 2) ? g_qq : g_kk) + b * NN + n, nrm);
}

// ---- K2: S[n][m] += sum_f Q[n,f]*K[m,f], LDS-staged streaming reduce.
// grid (F/(QCH*NCH), B) = (256, B), 512 thr = 8 waves -> 4 blk/CU.
// Per chunk: stage Q[32][QCH]+K into LDS with coalesced 512B-per-row
// loads, XOR-swizzled (col^(row&7)); 8 waves x 2 MFMA/chunk; acc
// carried across chunks; cross-wave LDS reduce + atomics.
__global__ void __launch_bounds__(512, 8)
k_sqk(const ushort_t* __restrict__ Q, const ushort_t* __restrict__ K) {
    __shared__ __align__(16) unsigned char smem[35904];
    ushort_t* sQ = (ushort_t*)smem;            // [32][QCH] bf16, swizzled
    ushort_t* sK = (ushort_t*)(smem + 16384);
    float (*redS)[64][17] = (float (*)[64][17])smem;  // overlay after compute

    const int t  = threadIdx.x;
    const int wv = t >> 6, ln = t & 63;
    const int b  = blockIdx.y;
    const size_t fbase = (size_t)blockIdx.x * (QCH * NCH);

    const int col = t & 31;          // 16B unit within a 512B row
    const int r0  = t >> 5;          // 0..15 (row group)
    const int rr  = ln & 31;         // MFMA row (n for A / m for B)
    const int khalf = ln >> 5;

    floatx16 acc;
#pragma unroll
    for (int r = 0; r < 16; ++r) acc[r] = 0.f;

    for (int ch = 0; ch < NCH; ++ch) {
        const size_t f0 = fbase + (size_t)ch * QCH;
        if (ch) __syncthreads();     // protect LDS from previous readers
#pragma unroll
        for (int pass = 0; pass < 2; ++pass) {
            const int r  = pass * 16 + r0;
            const int rc = (r < NN) ? r : (NN - 1);  // clamp: L2-merged dups
            const size_t g = ((size_t)b * NN + rc) * F + f0 + col * 8;
            const int lx = r * QCH + ((col ^ (r & 7)) * 8);
            *(us8*)&sQ[lx] = *(const us8*)(Q + g);
            *(us8*)&sK[lx] = *(const us8*)(K + g);
        }
        __syncthreads();
        // wave wv owns k-steps s = wv*2 + {0,1}
#pragma unroll
        for (int i = 0; i < 2; ++i) {
            const int cunit = (wv * 2 + i) * 2 + khalf;   // 16B unit 0..31
            const int lx = rr * QCH + ((cunit ^ (rr & 7)) * 8);
            short8 aq = *(const short8*)&sQ[lx];
            short8 bk = *(const short8*)&sK[lx];
            acc = __builtin_amdgcn_mfma_f32_32x32x16_bf16(aq, bk, acc, 0, 0, 0);
        }
    }

    __syncthreads();                 // before overlaying redS on sQ/sK
#pragma unroll
    for (int r = 0; r < 16; ++r) redS[wv][ln][r] = acc[r];
    __syncthreads();
    if (wv == 0) {
#pragma unroll
        for (int r = 0; r < 16; ++r) {
            float v = 0.f;
#pragma unroll
            for (int w = 0; w < 8; ++w) v += redS[w][ln][r];
            const int srow = (r & 3) + 8 * (r >> 2) + 4 * (ln >> 5); // C/D: m74/m101
            const int scol = ln & 31;
            if (srow < NN && scol < NN)
                atomicAdd(&g_S[((size_t)b * NN + srow) * NN + scol], v);
        }
    }
}

// ---- K3: normalize logits + softmax over m; writes TRANSPOSED att.
__global__ void k_softmax() {
    const int b = blockIdx.x, n = threadIdx.x;
    if (n >= NN) return;
    const float qn = fmaxf(sqrtf(g_qq[b * NN + n]), 1e-12f);
    float l[NN], mx = -1e30f;
#pragma unroll
    for (int m = 0; m < NN; ++m) {
        const float km = fmaxf(sqrtf(g_kk[b * NN + m]), 1e-12f);
        l[m] = g_S[((size_t)b * NN + n) * NN + m] / (qn * km);
        mx = fmaxf(mx, l[m]);
    }
    float s = 0.f;
#pragma unroll
    for (int m = 0; m < NN; ++m) { l[m] = expf(l[m] - mx); s += l[m]; }
    const float inv = 1.f / s;
#pragma unroll
    for (int m = 0; m < NN; ++m) g_attT[((size_t)b * NN + m) * NN + n] = l[m] * inv;
}

// ---- K4: out[b,d,n,p] = sum_m att[n,m] * V[b,m,(d,p)], packed-V form.
// grid (F/1024, B). Thread owns 4 consecutive packed g (= one lane-chunk
// of a k_proj store): f32x4 loads fully coalesced; acc = 25 x f32x4.
// decode: c0 = g>>8 = [tile(32)][sv(2)][ph(2)][ptv(2)][r4(4)].
__global__ void __launch_bounds__(256, 4)
k_outmix(const float* __restrict__ V, float* __restrict__ out) {
    const int tid = blockIdx.x * 256 + threadIdx.x;   // 0..65535 per b
    const int b   = blockIdx.y;
    const float* Vb = V + (size_t)b * NN * F + (size_t)tid * 4;
    const float* at = g_attT + b * NN * NN;

    f32x4 acc[NN];
#pragma unroll
    for (int n = 0; n < NN; ++n) acc[n] = 0.f;
#pragma unroll 5
    for (int m = 0; m < NN; ++m) {
        const f32x4 v = *(const f32x4*)(Vb + (size_t)m * F);
#pragma unroll
        for (int n = 0; n < NN; ++n) acc[n] += at[m * NN + n] * v;
    }

    const int ln = tid & 63, c0 = tid >> 6;
    const int r4 = c0 & 3, ptv = (c0 >> 2) & 1, ph = (c0 >> 3) & 1;
    const int sv = (c0 >> 4) & 1, tile = c0 >> 5;
    const int p  = tile * 128 + ph * 64 + ptv * 32 + (ln & 31);
    const int db = sv * 32 + 8 * r4 + 4 * (ln >> 5);  // rows db..db+3 (j)
#pragma unroll
    for (int n = 0; n < NN; ++n)
#pragma unroll
        for (int j = 0; j < 4; ++j)
            out[((size_t)(b * D + db + j) * NN + n) * HW + p] = acc[n][j];
}

extern "C" void kernel_launch(void* const* d_in, const int* in_sizes, int n_in,
                              void* d_out, int out_size, void* d_ws, size_t ws_size,
                              hipStream_t stream) {
    const float* x = (const float*)d_in[0];
    const float* W = (const float*)d_in[1];
    float* outf = (float*)d_out;

    // Q+K bf16 = 104,857,600 B = exactly out_size -> live in d_out (dead
    // before k_outmix rewrites it). V fp32 = 104,857,600 B -> d_ws.
    ushort_t* Q = (ushort_t*)d_out;
    ushort_t* K = Q + (size_t)B * NN * F;
    float*    V = (float*)d_ws;

    k_prep   <<<dim3(48),               256, 0, stream>>>(W);
    k_proj   <<<dim3(HW/PT, NN, B),     256, 0, stream>>>(x, Q, K, V);
    k_sqk    <<<dim3(F/(QCH*NCH), B),   512, 0, stream>>>(Q, K);
    k_softmax<<<dim3(B),                 64, 0, stream>>>();
    k_outmix <<<dim3(F/1024, B),        256, 0, stream>>>(V, outf);
}

// Round 9
// 356.351 us; speedup vs baseline: 1.4030x; 1.4030x over previous
//
#include <hip/hip_runtime.h>

// Problem constants (fixed by reference setup_inputs)
#define B   4
#define C   64      // input channels
#define D   64      // dims per head of q/k/v
#define NN  25      // angRes*angRes angular positions
#define HW  4096    // h*w
#define F   (D*HW)  // 262144 feature dim per head, flattened

#define PT  64      // p-tile per block in k_proj (16KB LDS -> ~8 blk/CU)
#define QCH 256     // f elems staged per chunk in k_sqk
#define NCH 4       // chunks per k_sqk block -> block covers 1024 f

typedef unsigned short ushort_t;
typedef unsigned int   uint_t;
typedef __attribute__((ext_vector_type(8)))  short  short8;   // 8 bf16 (4 VGPRs)
typedef __attribute__((ext_vector_type(8)))  unsigned short us8;
typedef __attribute__((ext_vector_type(16))) float  floatx16; // MFMA 32x32 accum
typedef __attribute__((ext_vector_type(4)))  float  f32x4;
typedef __attribute__((ext_vector_type(4)))  unsigned short us4;

// Compensated bf16 weight splits (W = hi + lo, |err| ~ 2^-17 rel), native
// [row][c] layout. Rows 0..127 = q,k; Wv rows 0..63 = v.
__device__ ushort_t g_Wthi[128 * C];
__device__ ushort_t g_Wtlo[128 * C];
__device__ ushort_t g_Wvhi[D * C];
__device__ ushort_t g_Wvlo[D * C];

// Tiny cross-kernel accumulators (20KB) -- frees d_out to host Q,K.
__device__ float g_S[B * NN * NN];
__device__ float g_qq[B * NN];
__device__ float g_kk[B * NN];
__device__ float g_attT[B * NN * NN];   // transposed att [b][m][n]

static __device__ __forceinline__ ushort_t f2bf(float f) {
    uint_t u = __float_as_uint(f);
    u += 0x7FFFu + ((u >> 16) & 1u);   // round-to-nearest-even
    return (ushort_t)(u >> 16);
}
static __device__ __forceinline__ float bf2f(ushort_t h) {
    return __uint_as_float((uint_t)h << 16);
}

// LDS elem index for transposed tile xT[p][c] (bf16, PT rows of 64 c).
// 8-c granules XOR'd by (p&7) -- measured best (2.05M conflict-cy vs 4.1M
// for (p>>2)&7). ds_write_b64 (4c) and ds_read_b128 (8c) stay intact.
static __device__ __forceinline__ int lds_x(int p, int c) {
    return p * 64 + ((((c >> 3) ^ (p & 7)) << 3) | (c & 7));
}

// ---- Kp: zero S/qq/kk + split all 192 W rows into bf16 hi/lo. 48 blocks.
__global__ void k_prep(const float* __restrict__ W) {
    int i = blockIdx.x * 256 + threadIdx.x;          // over 192*64
    if (i < 2500)      g_S[i] = 0.f;
    else if (i < 2600) g_qq[i - 2500] = 0.f;
    else if (i < 2700) g_kk[i - 2600] = 0.f;
    if (i < 128 * 64) {
        float w = W[i];                              // W[d'][c], native index
        ushort_t hi = f2bf(w);
        g_Wthi[i] = hi;
        g_Wtlo[i] = f2bf(w - bf2f(hi));
    } else if (i < 192 * 64) {
        float w = W[i];                              // v rows 128..191
        int j = i - 128 * 64;
        ushort_t hi = f2bf(w);
        g_Wvhi[j] = hi;
        g_Wvlo[j] = f2bf(w - bf2f(hi));
    }
}

// ---- K1: fused Q,K,V projection via compensated-bf16 MFMA + fused norms.
// grid (HW/PT, NN, B) = 6400 blocks, 256 thr = 4 waves, 16KB LDS,
// bounds(256,4). PT=64 halves LDS vs round-6 (32KB->16KB) so HW occupancy
// can float to ~8 blk/CU (32 waves/CU; round-6 measured 34% occupancy,
// latency-bound, all pipes <35%). bounds stays (256,4): round-3 proved
// bounds(256,8) strangles the allocator (VGPR 32, 131us). LDS staging
// kept: round-8's LDS-less variant quadrupled x fetch (337MB) and broke
// write-combining (477MB writes) -> 300us. Rounding points unchanged.
// Packed layouts (f opaque to k_sqk; k_outmix decodes):
//   Q/K elem f = [tile(64)][slab(2)][pt(2)][r4(4)][ln(64)][j(4)]
//   V   elem g = [tile(64)][sv(2)][ptv(2)][r4(4)][ln(64)][j(4)]
__global__ void __launch_bounds__(256, 4)
k_proj(const float* __restrict__ x,
       ushort_t* __restrict__ Q, ushort_t* __restrict__ K,
       float* __restrict__ V) {
    __shared__ ushort_t sXhi[PT * 64];
    __shared__ ushort_t sXlo[PT * 64];

    const int t  = threadIdx.x;
    const int wv = t >> 6, ln = t & 63;
    const int n  = blockIdx.y, b = blockIdx.z;
    const int tile = blockIdx.x;
    const int gp0  = tile * PT;
    const size_t cstride = (size_t)NN * HW;

    // ---- QK A-fragments first (independent of LDS -> overlap the stage).
    const int row = ln & 31, kh8 = (ln >> 5) * 8, d0 = wv * 32;
    short8 ahi[4], alo[4];
#pragma unroll
    for (int ks = 0; ks < 4; ++ks) {
        ahi[ks] = *(const short8*)&g_Wthi[(d0 + row) * 64 + ks * 16 + kh8];
        alo[ks] = *(const short8*)&g_Wtlo[(d0 + row) * 64 + ks * 16 + kh8];
    }

    // ---- stage: wave wv loads c in [wv*16, wv*16+16) for p = ln (64 p),
    // converts to hi/lo, writes transposed into LDS (coalesced 256B loads).
    {
        const int c16 = wv * 16;
#pragma unroll
        for (int cg = 0; cg < 4; ++cg) {
            const int c4 = c16 + cg * 4;
            const float* xc = x + ((size_t)(b * C + c4) * NN + n) * HW + gp0;
            float v[4];
#pragma unroll
            for (int i = 0; i < 4; ++i) v[i] = xc[(size_t)i * cstride + ln];
            us4 h, l;
#pragma unroll
            for (int i = 0; i < 4; ++i) {
                ushort_t hi = f2bf(v[i]);
                h[i] = hi;
                l[i] = f2bf(v[i] - bf2f(hi));
            }
            *(us4*)&sXhi[lds_x(ln, c4)] = h;
            *(us4*)&sXlo[lds_x(ln, c4)] = l;
        }
    }
    __syncthreads();

    // ---- QK phase: wave wv owns slab d0 (Q slabs wv<2, K slabs wv>=2),
    // 2 p-tiles x 12 MFMA; packed us4 stores; fp32 pre-round norms.
    ushort_t* __restrict__ O = (wv < 2) ? Q : K;
    const int slab = wv & 1;
    const size_t nbase = (size_t)(b * NN + n) * F;

    float nrm = 0.f;
#pragma unroll
    for (int pt = 0; pt < 2; ++pt) {
        const int pcol = pt * 32 + row;
        floatx16 acc;
#pragma unroll
        for (int r = 0; r < 16; ++r) acc[r] = 0.f;
#pragma unroll
        for (int ks = 0; ks < 4; ++ks) {
            const int c0 = ks * 16 + kh8;
            short8 bhi = *(const short8*)&sXhi[lds_x(pcol, c0)];
            short8 blo = *(const short8*)&sXlo[lds_x(pcol, c0)];
            acc = __builtin_amdgcn_mfma_f32_32x32x16_bf16(ahi[ks], bhi, acc, 0, 0, 0);
            acc = __builtin_amdgcn_mfma_f32_32x32x16_bf16(alo[ks], bhi, acc, 0, 0, 0);
            acc = __builtin_amdgcn_mfma_f32_32x32x16_bf16(ahi[ks], blo, acc, 0, 0, 0);
        }
#pragma unroll
        for (int r4 = 0; r4 < 4; ++r4) {
            us4 h;
#pragma unroll
            for (int j = 0; j < 4; ++j) {
                const float a = acc[r4 * 4 + j];
                nrm += a * a;
                h[j] = f2bf(a);
            }
            *(us4*)&O[nbase + (((size_t)((tile * 2 + slab) * 8 + pt * 4 + r4)) << 8)
                      + ln * 4] = h;
        }
    }
    for (int off = 32; off > 0; off >>= 1) nrm += __shfl_xor(nrm, off);
    if (ln == 0) atomicAdd(((wv < 2) ? g_qq : g_kk) + b * NN + n, nrm);

    // ---- V phase: wave wv owns unit (sv = wv&1, ptv = wv>>1); 12 MFMA;
    // fp32 packed f32x4 stores. LDS is read-only now -> no extra barrier.
    {
        const int sv = wv & 1, ptv = (wv >> 1) & 1;
        short8 vhi[4], vlo[4];
#pragma unroll
        for (int ks = 0; ks < 4; ++ks) {
            vhi[ks] = *(const short8*)&g_Wvhi[(sv * 32 + row) * 64 + ks * 16 + kh8];
            vlo[ks] = *(const short8*)&g_Wvlo[(sv * 32 + row) * 64 + ks * 16 + kh8];
        }
        const int pcol = ptv * 32 + row;
        floatx16 av;
#pragma unroll
        for (int r = 0; r < 16; ++r) av[r] = 0.f;
#pragma unroll
        for (int ks = 0; ks < 4; ++ks) {
            const int c0 = ks * 16 + kh8;
            short8 bhi = *(const short8*)&sXhi[lds_x(pcol, c0)];
            short8 blo = *(const short8*)&sXlo[lds_x(pcol, c0)];
            av = __builtin_amdgcn_mfma_f32_32x32x16_bf16(vhi[ks], bhi, av, 0, 0, 0);
            av = __builtin_amdgcn_mfma_f32_32x32x16_bf16(vlo[ks], bhi, av, 0, 0, 0);
            av = __builtin_amdgcn_mfma_f32_32x32x16_bf16(vhi[ks], blo, av, 0, 0, 0);
        }
#pragma unroll
        for (int r4 = 0; r4 < 4; ++r4) {
            f32x4 vv;
#pragma unroll
            for (int j = 0; j < 4; ++j) vv[j] = av[r4 * 4 + j];
            *(f32x4*)&V[nbase + (((size_t)((tile * 4 + sv * 2 + ptv) * 4 + r4)) << 8)
                        + ln * 4] = vv;
        }
    }
}

// ---- K2: S[n][m] += sum_f Q[n,f]*K[m,f], LDS-staged streaming reduce.
// grid (F/(QCH*NCH), B) = (256, B), 512 thr = 8 waves -> 4 blk/CU.
// Per chunk: stage Q[32][QCH]+K into LDS with coalesced 512B-per-row
// loads, XOR-swizzled (col^(row&7)); 8 waves x 2 MFMA/chunk; acc
// carried across chunks; cross-wave LDS reduce + atomics.
__global__ void __launch_bounds__(512, 8)
k_sqk(const ushort_t* __restrict__ Q, const ushort_t* __restrict__ K) {
    __shared__ __align__(16) unsigned char smem[35904];
    ushort_t* sQ = (ushort_t*)smem;            // [32][QCH] bf16, swizzled
    ushort_t* sK = (ushort_t*)(smem + 16384);
    float (*redS)[64][17] = (float (*)[64][17])smem;  // overlay after compute

    const int t  = threadIdx.x;
    const int wv = t >> 6, ln = t & 63;
    const int b  = blockIdx.y;
    const size_t fbase = (size_t)blockIdx.x * (QCH * NCH);

    const int col = t & 31;          // 16B unit within a 512B row
    const int r0  = t >> 5;          // 0..15 (row group)
    const int rr  = ln & 31;         // MFMA row (n for A / m for B)
    const int khalf = ln >> 5;

    floatx16 acc;
#pragma unroll
    for (int r = 0; r < 16; ++r) acc[r] = 0.f;

    for (int ch = 0; ch < NCH; ++ch) {
        const size_t f0 = fbase + (size_t)ch * QCH;
        if (ch) __syncthreads();     // protect LDS from previous readers
#pragma unroll
        for (int pass = 0; pass < 2; ++pass) {
            const int r  = pass * 16 + r0;
            const int rc = (r < NN) ? r : (NN - 1);  // clamp: L2-merged dups
            const size_t g = ((size_t)b * NN + rc) * F + f0 + col * 8;
            const int lx = r * QCH + ((col ^ (r & 7)) * 8);
            *(us8*)&sQ[lx] = *(const us8*)(Q + g);
            *(us8*)&sK[lx] = *(const us8*)(K + g);
        }
        __syncthreads();
        // wave wv owns k-steps s = wv*2 + {0,1}
#pragma unroll
        for (int i = 0; i < 2; ++i) {
            const int cunit = (wv * 2 + i) * 2 + khalf;   // 16B unit 0..31
            const int lx = rr * QCH + ((cunit ^ (rr & 7)) * 8);
            short8 aq = *(const short8*)&sQ[lx];
            short8 bk = *(const short8*)&sK[lx];
            acc = __builtin_amdgcn_mfma_f32_32x32x16_bf16(aq, bk, acc, 0, 0, 0);
        }
    }

    __syncthreads();                 // before overlaying redS on sQ/sK
#pragma unroll
    for (int r = 0; r < 16; ++r) redS[wv][ln][r] = acc[r];
    __syncthreads();
    if (wv == 0) {
#pragma unroll
        for (int r = 0; r < 16; ++r) {
            float v = 0.f;
#pragma unroll
            for (int w = 0; w < 8; ++w) v += redS[w][ln][r];
            const int srow = (r & 3) + 8 * (r >> 2) + 4 * (ln >> 5); // C/D: m74/m101
            const int scol = ln & 31;
            if (srow < NN && scol < NN)
                atomicAdd(&g_S[((size_t)b * NN + srow) * NN + scol], v);
        }
    }
}

// ---- K3: normalize logits + softmax over m; writes TRANSPOSED att.
__global__ void k_softmax() {
    const int b = blockIdx.x, n = threadIdx.x;
    if (n >= NN) return;
    const float qn = fmaxf(sqrtf(g_qq[b * NN + n]), 1e-12f);
    float l[NN], mx = -1e30f;
#pragma unroll
    for (int m = 0; m < NN; ++m) {
        const float km = fmaxf(sqrtf(g_kk[b * NN + m]), 1e-12f);
        l[m] = g_S[((size_t)b * NN + n) * NN + m] / (qn * km);
        mx = fmaxf(mx, l[m]);
    }
    float s = 0.f;
#pragma unroll
    for (int m = 0; m < NN; ++m) { l[m] = expf(l[m] - mx); s += l[m]; }
    const float inv = 1.f / s;
#pragma unroll
    for (int m = 0; m < NN; ++m) g_attT[((size_t)b * NN + m) * NN + n] = l[m] * inv;
}

// ---- K4: out[b,d,n,p] = sum_m att[n,m] * V[b,m,(d,p)], packed-V form.
// grid (F/1024, B). Thread owns 4 consecutive packed g (= one lane-chunk
// of a k_proj store): f32x4 loads fully coalesced; acc = 25 x f32x4.
// decode: c0 = g>>8 = [tile(64)][sv(2)][ptv(2)][r4(4)].
__global__ void __launch_bounds__(256, 4)
k_outmix(const float* __restrict__ V, float* __restrict__ out) {
    const int tid = blockIdx.x * 256 + threadIdx.x;   // 0..65535 per b
    const int b   = blockIdx.y;
    const float* Vb = V + (size_t)b * NN * F + (size_t)tid * 4;
    const float* at = g_attT + b * NN * NN;

    f32x4 acc[NN];
#pragma unroll
    for (int n = 0; n < NN; ++n) acc[n] = 0.f;
#pragma unroll 5
    for (int m = 0; m < NN; ++m) {
        const f32x4 v = *(const f32x4*)(Vb + (size_t)m * F);
#pragma unroll
        for (int n = 0; n < NN; ++n) acc[n] += at[m * NN + n] * v;
    }

    const int ln = tid & 63, c0 = tid >> 6;
    const int r4 = c0 & 3, ptv = (c0 >> 2) & 1, sv = (c0 >> 3) & 1;
    const int tile = c0 >> 4;
    const int p  = tile * 64 + ptv * 32 + (ln & 31);
    const int db = sv * 32 + 8 * r4 + 4 * (ln >> 5);  // rows db..db+3 (j)
#pragma unroll
    for (int n = 0; n < NN; ++n)
#pragma unroll
        for (int j = 0; j < 4; ++j)
            out[((size_t)(b * D + db + j) * NN + n) * HW + p] = acc[n][j];
}

extern "C" void kernel_launch(void* const* d_in, const int* in_sizes, int n_in,
                              void* d_out, int out_size, void* d_ws, size_t ws_size,
                              hipStream_t stream) {
    const float* x = (const float*)d_in[0];
    const float* W = (const float*)d_in[1];
    float* outf = (float*)d_out;

    // Q+K bf16 = 104,857,600 B = exactly out_size -> live in d_out (dead
    // before k_outmix rewrites it). V fp32 = 104,857,600 B -> d_ws.
    ushort_t* Q = (ushort_t*)d_out;
    ushort_t* K = Q + (size_t)B * NN * F;
    float*    V = (float*)d_ws;

    k_prep   <<<dim3(48),               256, 0, stream>>>(W);
    k_proj   <<<dim3(HW/PT, NN, B),     256, 0, stream>>>(x, Q, K, V);
    k_sqk    <<<dim3(F/(QCH*NCH), B),   512, 0, stream>>>(Q, K);
    k_softmax<<<dim3(B),                 64, 0, stream>>>();
    k_outmix <<<dim3(F/1024, B),        256, 0, stream>>>(V, outf);
}

// Round 11
// 301.624 us; speedup vs baseline: 1.6576x; 1.1814x over previous
//
#include <hip/hip_runtime.h>

// Problem constants (fixed by reference setup_inputs)
#define B   4
#define C   64      // input channels
#define D   64      // dims per head of q/k/v
#define NN  25      // angRes*angRes angular positions
#define HW  4096    // h*w
#define F   (D*HW)  // 262144 feature dim per head, flattened

#define PT  128     // p-tile per block in k_proj (32KB LDS). PT=64 tried
                    // twice (r3, r9): VGPR collapse, regression. Keep 128.
#define QCH 256     // f elems staged per chunk in k_sqk
#define NCH 4       // chunks per k_sqk block -> block covers 1024 f

typedef unsigned short ushort_t;
typedef unsigned int   uint_t;
typedef __attribute__((ext_vector_type(8)))  short  short8;   // 8 bf16 (4 VGPRs)
typedef __attribute__((ext_vector_type(8)))  unsigned short us8;
typedef __attribute__((ext_vector_type(16))) float  floatx16; // MFMA 32x32 accum
typedef __attribute__((ext_vector_type(4)))  float  f32x4;
typedef __attribute__((ext_vector_type(4)))  unsigned short us4;

// Compensated bf16 weight splits (W = hi + lo, |err| ~ 2^-17 rel), native
// [row][c] layout. Rows 0..127 = q,k; Wv rows 0..63 = v.
__device__ ushort_t g_Wthi[128 * C];
__device__ ushort_t g_Wtlo[128 * C];
__device__ ushort_t g_Wvhi[D * C];
__device__ ushort_t g_Wvlo[D * C];

// Tiny cross-kernel accumulators (20KB) -- frees d_out to host Q,K.
__device__ float g_S[B * NN * NN];
__device__ float g_qq[B * NN];
__device__ float g_kk[B * NN];
__device__ float g_attT[B * NN * NN];   // transposed att [b][m][n]

static __device__ __forceinline__ ushort_t f2bf(float f) {
    uint_t u = __float_as_uint(f);
    u += 0x7FFFu + ((u >> 16) & 1u);   // round-to-nearest-even
    return (ushort_t)(u >> 16);
}
static __device__ __forceinline__ float bf2f(ushort_t h) {
    return __uint_as_float((uint_t)h << 16);
}

// LDS elem index for transposed tile xT[p][c] (bf16, PT rows of 64 c).
// 8-c granules XOR'd by (p&7) -- measured best (2.05M conflict-cy vs 4.1M
// for (p>>2)&7). ds_write_b64 (4c) and ds_read_b128 (8c) stay intact.
static __device__ __forceinline__ int lds_x(int p, int c) {
    return p * 64 + ((((c >> 3) ^ (p & 7)) << 3) | (c & 7));
}

// ---- Kp: zero S/qq/kk + split all 192 W rows into bf16 hi/lo. 48 blocks.
__global__ void k_prep(const float* __restrict__ W) {
    int i = blockIdx.x * 256 + threadIdx.x;          // over 192*64
    if (i < 2500)      g_S[i] = 0.f;
    else if (i < 2600) g_qq[i - 2500] = 0.f;
    else if (i < 2700) g_kk[i - 2600] = 0.f;
    if (i < 128 * 64) {
        float w = W[i];                              // W[d'][c], native index
        ushort_t hi = f2bf(w);
        g_Wthi[i] = hi;
        g_Wtlo[i] = f2bf(w - bf2f(hi));
    } else if (i < 192 * 64) {
        float w = W[i];                              // v rows 128..191
        int j = i - 128 * 64;
        ushort_t hi = f2bf(w);
        g_Wvhi[j] = hi;
        g_Wvlo[j] = f2bf(w - bf2f(hi));
    }
}

// ---- K1: fused Q,K,V projection via compensated-bf16 MFMA + fused norms.
// grid (HW/PT, NN, B) = 3200 blocks, 256 thr = 4 waves, 32KB LDS,
// bounds(256,4). Round-6 body EXCEPT the stage: all 32 x-loads are issued
// into v[32] BEFORE any convert/ds_write (round-6 interleaved
// load->convert->write per 4 loads; at VGPR=64 only ~4 loads were in
// flight and each wave serially ate ~8x memory latency -> all pipes <15%).
// A-fragment loads moved AFTER the barrier: frees 32 VGPR during the
// stage and overlaps the (L1-hot) W loads with the ds_read phase.
// Packed layouts (f opaque to k_sqk; k_outmix decodes):
//   Q/K elem f = [tile(32)][slab(2)][pt(4)][r4(4)][ln(64)][j(4)]
//   V   elem g = [tile(32)][sv(2)][ph(2)][ptv(2)][r4(4)][ln(64)][j(4)]
__global__ void __launch_bounds__(256, 4)
k_proj(const float* __restrict__ x,
       ushort_t* __restrict__ Q, ushort_t* __restrict__ K,
       float* __restrict__ V) {
    __shared__ ushort_t sXhi[PT * 64];
    __shared__ ushort_t sXlo[PT * 64];

    const int t  = threadIdx.x;
    const int wv = t >> 6, ln = t & 63;
    const int n  = blockIdx.y, b = blockIdx.z;
    const int tile = blockIdx.x;
    const int gp0  = tile * PT;
    const int row = ln & 31, kh8 = (ln >> 5) * 8;
    const size_t cstride = (size_t)NN * HW;

    // ---- stage, issue-early form: wave wv covers c in [wv*16, wv*16+16)
    // for 128 p. 32 independent loads into v[32] (static idx -> registers),
    // THEN convert to hi/lo and write LDS transposed.
    {
        float v[32];
        const int c16 = wv * 16;
#pragma unroll
        for (int cg = 0; cg < 4; ++cg) {
            const int c4 = c16 + cg * 4;
            const float* xc = x + ((size_t)(b * C + c4) * NN + n) * HW + gp0;
#pragma unroll
            for (int ph = 0; ph < 2; ++ph)
#pragma unroll
                for (int i = 0; i < 4; ++i)
                    v[cg * 8 + ph * 4 + i] =
                        xc[(size_t)i * cstride + ph * 64 + ln];
        }
#pragma unroll
        for (int cg = 0; cg < 4; ++cg) {
            const int c4 = c16 + cg * 4;
#pragma unroll
            for (int ph = 0; ph < 2; ++ph) {
                const int p = ph * 64 + ln;
                us4 h, l;
#pragma unroll
                for (int i = 0; i < 4; ++i) {
                    const float val = v[cg * 8 + ph * 4 + i];
                    const ushort_t hi = f2bf(val);
                    h[i] = hi;
                    l[i] = f2bf(val - bf2f(hi));
                }
                *(us4*)&sXhi[lds_x(p, c4)] = h;
                *(us4*)&sXlo[lds_x(p, c4)] = l;
            }
        }
    }
    __syncthreads();

    // ---- QK A-fragments (L1-hot; loads overlap the first ds_reads).
    const int d0 = wv * 32;
    short8 ahi[4], alo[4];
#pragma unroll
    for (int ks = 0; ks < 4; ++ks) {
        ahi[ks] = *(const short8*)&g_Wthi[(d0 + row) * 64 + ks * 16 + kh8];
        alo[ks] = *(const short8*)&g_Wtlo[(d0 + row) * 64 + ks * 16 + kh8];
    }

    // ---- QK phase: 4 p-tiles, packed epilogue stores.
    ushort_t* __restrict__ O = (wv < 2) ? Q : K;
    const int slab = (wv < 2) ? wv : wv - 2;
    const size_t nbase = (size_t)(b * NN + n) * F;

    float nrm = 0.f;
#pragma unroll
    for (int pt = 0; pt < 4; ++pt) {
        const int pcol = pt * 32 + row;
        floatx16 acc;
#pragma unroll
        for (int r = 0; r < 16; ++r) acc[r] = 0.f;
#pragma unroll
        for (int ks = 0; ks < 4; ++ks) {
            const int c0 = ks * 16 + kh8;
            short8 bhi = *(const short8*)&sXhi[lds_x(pcol, c0)];
            short8 blo = *(const short8*)&sXlo[lds_x(pcol, c0)];
            acc = __builtin_amdgcn_mfma_f32_32x32x16_bf16(ahi[ks], bhi, acc, 0, 0, 0);
            acc = __builtin_amdgcn_mfma_f32_32x32x16_bf16(alo[ks], bhi, acc, 0, 0, 0);
            acc = __builtin_amdgcn_mfma_f32_32x32x16_bf16(ahi[ks], blo, acc, 0, 0, 0);
        }
#pragma unroll
        for (int r4 = 0; r4 < 4; ++r4) {
            us4 h;
#pragma unroll
            for (int j = 0; j < 4; ++j) {
                const float a = acc[r4 * 4 + j];
                nrm += a * a;
                h[j] = f2bf(a);
            }
            *(us4*)&O[nbase + (((size_t)((tile * 2 + slab) * 16 + pt * 4 + r4)) << 8)
                      + ln * 4] = h;
        }
    }
    for (int off = 32; off > 0; off >>= 1) nrm += __shfl_xor(nrm, off);
    if (ln == 0) atomicAdd(((wv < 2) ? g_qq : g_kk) + b * NN + n, nrm);

    // ---- V phase: slab sv, p-half ph; fp32 packed stores. LDS read-only.
    {
        const int sv = wv & 1, ph = wv >> 1;
        short8 vhi[4], vlo[4];
#pragma unroll
        for (int ks = 0; ks < 4; ++ks) {
            vhi[ks] = *(const short8*)&g_Wvhi[(sv * 32 + row) * 64 + ks * 16 + kh8];
            vlo[ks] = *(const short8*)&g_Wvlo[(sv * 32 + row) * 64 + ks * 16 + kh8];
        }
#pragma unroll
        for (int pt = 0; pt < 2; ++pt) {
            const int pcol = ph * 64 + pt * 32 + row;
            floatx16 av;
#pragma unroll
            for (int r = 0; r < 16; ++r) av[r] = 0.f;
#pragma unroll
            for (int ks = 0; ks < 4; ++ks) {
                const int c0 = ks * 16 + kh8;
                short8 bhi = *(const short8*)&sXhi[lds_x(pcol, c0)];
                short8 blo = *(const short8*)&sXlo[lds_x(pcol, c0)];
                av = __builtin_amdgcn_mfma_f32_32x32x16_bf16(vhi[ks], bhi, av, 0, 0, 0);
                av = __builtin_amdgcn_mfma_f32_32x32x16_bf16(vlo[ks], bhi, av, 0, 0, 0);
                av = __builtin_amdgcn_mfma_f32_32x32x16_bf16(vhi[ks], blo, av, 0, 0, 0);
            }
#pragma unroll
            for (int r4 = 0; r4 < 4; ++r4) {
                f32x4 vv;
#pragma unroll
                for (int j = 0; j < 4; ++j) vv[j] = av[r4 * 4 + j];
                *(f32x4*)&V[nbase + (((size_t)((((tile * 2 + sv) * 2 + ph) * 2 + pt) * 4
                    + r4)) << 8) + ln * 4] = vv;
            }
        }
    }
}

// ---- K2: S[n][m] += sum_f Q[n,f]*K[m,f], LDS-staged streaming reduce.
// grid (F/(QCH*NCH), B) = (256, B), 512 thr = 8 waves -> 4 blk/CU.
// Per chunk: stage Q[32][QCH]+K into LDS with coalesced 512B-per-row
// loads, XOR-swizzled (col^(row&7)); 8 waves x 2 MFMA/chunk; acc
// carried across chunks; cross-wave LDS reduce + atomics.
__global__ void __launch_bounds__(512, 8)
k_sqk(const ushort_t* __restrict__ Q, const ushort_t* __restrict__ K) {
    __shared__ __align__(16) unsigned char smem[35904];
    ushort_t* sQ = (ushort_t*)smem;            // [32][QCH] bf16, swizzled
    ushort_t* sK = (ushort_t*)(smem + 16384);
    float (*redS)[64][17] = (float (*)[64][17])smem;  // overlay after compute

    const int t  = threadIdx.x;
    const int wv = t >> 6, ln = t & 63;
    const int b  = blockIdx.y;
    const size_t fbase = (size_t)blockIdx.x * (QCH * NCH);

    const int col = t & 31;          // 16B unit within a 512B row
    const int r0  = t >> 5;          // 0..15 (row group)
    const int rr  = ln & 31;         // MFMA row (n for A / m for B)
    const int khalf = ln >> 5;

    floatx16 acc;
#pragma unroll
    for (int r = 0; r < 16; ++r) acc[r] = 0.f;

    for (int ch = 0; ch < NCH; ++ch) {
        const size_t f0 = fbase + (size_t)ch * QCH;
        if (ch) __syncthreads();     // protect LDS from previous readers
#pragma unroll
        for (int pass = 0; pass < 2; ++pass) {
            const int r  = pass * 16 + r0;
            const int rc = (r < NN) ? r : (NN - 1);  // clamp: L2-merged dups
            const size_t g = ((size_t)b * NN + rc) * F + f0 + col * 8;
            const int lx = r * QCH + ((col ^ (r & 7)) * 8);
            *(us8*)&sQ[lx] = *(const us8*)(Q + g);
            *(us8*)&sK[lx] = *(const us8*)(K + g);
        }
        __syncthreads();
        // wave wv owns k-steps s = wv*2 + {0,1}
#pragma unroll
        for (int i = 0; i < 2; ++i) {
            const int cunit = (wv * 2 + i) * 2 + khalf;   // 16B unit 0..31
            const int lx = rr * QCH + ((cunit ^ (rr & 7)) * 8);
            short8 aq = *(const short8*)&sQ[lx];
            short8 bk = *(const short8*)&sK[lx];
            acc = __builtin_amdgcn_mfma_f32_32x32x16_bf16(aq, bk, acc, 0, 0, 0);
        }
    }

    __syncthreads();                 // before overlaying redS on sQ/sK
#pragma unroll
    for (int r = 0; r < 16; ++r) redS[wv][ln][r] = acc[r];
    __syncthreads();
    if (wv == 0) {
#pragma unroll
        for (int r = 0; r < 16; ++r) {
            float v = 0.f;
#pragma unroll
            for (int w = 0; w < 8; ++w) v += redS[w][ln][r];
            const int srow = (r & 3) + 8 * (r >> 2) + 4 * (ln >> 5); // C/D: m74/m101
            const int scol = ln & 31;
            if (srow < NN && scol < NN)
                atomicAdd(&g_S[((size_t)b * NN + srow) * NN + scol], v);
        }
    }
}

// ---- K3: normalize logits + softmax over m; writes TRANSPOSED att.
__global__ void k_softmax() {
    const int b = blockIdx.x, n = threadIdx.x;
    if (n >= NN) return;
    const float qn = fmaxf(sqrtf(g_qq[b * NN + n]), 1e-12f);
    float l[NN], mx = -1e30f;
#pragma unroll
    for (int m = 0; m < NN; ++m) {
        const float km = fmaxf(sqrtf(g_kk[b * NN + m]), 1e-12f);
        l[m] = g_S[((size_t)b * NN + n) * NN + m] / (qn * km);
        mx = fmaxf(mx, l[m]);
    }
    float s = 0.f;
#pragma unroll
    for (int m = 0; m < NN; ++m) { l[m] = expf(l[m] - mx); s += l[m]; }
    const float inv = 1.f / s;
#pragma unroll
    for (int m = 0; m < NN; ++m) g_attT[((size_t)b * NN + m) * NN + n] = l[m] * inv;
}

// ---- K4: out[b,d,n,p] = sum_m att[n,m] * V[b,m,(d,p)], packed-V form.
// grid (F/1024, B). Thread owns 4 consecutive packed g (= one lane-chunk
// of a k_proj store): f32x4 loads fully coalesced; acc = 25 x f32x4.
// decode: c0 = g>>8 = [tile(32)][sv(2)][ph(2)][ptv(2)][r4(4)].
__global__ void __launch_bounds__(256, 4)
k_outmix(const float* __restrict__ V, float* __restrict__ out) {
    const int tid = blockIdx.x * 256 + threadIdx.x;   // 0..65535 per b
    const int b   = blockIdx.y;
    const float* Vb = V + (size_t)b * NN * F + (size_t)tid * 4;
    const float* at = g_attT + b * NN * NN;

    f32x4 acc[NN];
#pragma unroll
    for (int n = 0; n < NN; ++n) acc[n] = 0.f;
#pragma unroll 5
    for (int m = 0; m < NN; ++m) {
        const f32x4 v = *(const f32x4*)(Vb + (size_t)m * F);
#pragma unroll
        for (int n = 0; n < NN; ++n) acc[n] += at[m * NN + n] * v;
    }

    const int ln = tid & 63, c0 = tid >> 6;
    const int r4 = c0 & 3, ptv = (c0 >> 2) & 1, ph = (c0 >> 3) & 1;
    const int sv = (c0 >> 4) & 1, tile = c0 >> 5;
    const int p  = tile * 128 + ph * 64 + ptv * 32 + (ln & 31);
    const int db = sv * 32 + 8 * r4 + 4 * (ln >> 5);  // rows db..db+3 (j)
#pragma unroll
    for (int n = 0; n < NN; ++n)
#pragma unroll
        for (int j = 0; j < 4; ++j)
            out[((size_t)(b * D + db + j) * NN + n) * HW + p] = acc[n][j];
}

extern "C" void kernel_launch(void* const* d_in, const int* in_sizes, int n_in,
                              void* d_out, int out_size, void* d_ws, size_t ws_size,
                              hipStream_t stream) {
    const float* x = (const float*)d_in[0];
    const float* W = (const float*)d_in[1];
    float* outf = (float*)d_out;

    // Q+K bf16 = 104,857,600 B = exactly out_size -> live in d_out (dead
    // before k_outmix rewrites it). V fp32 = 104,857,600 B -> d_ws.
    ushort_t* Q = (ushort_t*)d_out;
    ushort_t* K = Q + (size_t)B * NN * F;
    float*    V = (float*)d_ws;

    k_prep   <<<dim3(48),               256, 0, stream>>>(W);
    k_proj   <<<dim3(HW/PT, NN, B),     256, 0, stream>>>(x, Q, K, V);
    k_sqk    <<<dim3(F/(QCH*NCH), B),   512, 0, stream>>>(Q, K);
    k_softmax<<<dim3(B),                 64, 0, stream>>>();
    k_outmix <<<dim3(F/1024, B),        256, 0, stream>>>(V, outf);
}